// Round 1
// baseline (704.234 us; speedup 1.0000x reference)
//
#include <hip/hip_runtime.h>

// VanillaGNN: out = A @ relu(A @ (x@W1)) @ W2  with A[dst,src] += val
// N=100000 nodes, E=1.6M edges, IN=128, HID=128, OUT=64, all f32.

#define IN_CH  128
#define HID_CH 128
#define OUT_CH 64

// ---------------- CSR build ----------------

__global__ void hist_kernel(const int* __restrict__ dst, int* __restrict__ counts, int E) {
    int i = blockIdx.x * blockDim.x + threadIdx.x;
    if (i < E) atomicAdd(&counts[dst[i]], 1);
}

// Exclusive scan of counts (in counts_cursor) -> row_ptr[0..n], and leaves the
// exclusive offsets in counts_cursor as the scatter cursors. Single block.
__global__ __launch_bounds__(1024) void scan_kernel(int* __restrict__ counts_cursor,
                                                    int* __restrict__ row_ptr, int n) {
    __shared__ int warp_excl[16];
    __shared__ int warp_total;
    int t = threadIdx.x;
    int lane = t & 63;
    int w = t >> 6;
    int carry = 0;
    for (int base = 0; base < n; base += 1024) {
        int i = base + t;
        int v = (i < n) ? counts_cursor[i] : 0;
        int s = v;
        #pragma unroll
        for (int d = 1; d < 64; d <<= 1) {
            int u = __shfl_up(s, d, 64);
            if (lane >= d) s += u;
        }
        if (lane == 63) warp_excl[w] = s;
        __syncthreads();
        if (t == 0) {
            int run = 0;
            #pragma unroll
            for (int j = 0; j < 16; ++j) { int x = warp_excl[j]; warp_excl[j] = run; run += x; }
            warp_total = run;
        }
        __syncthreads();
        int excl = carry + warp_excl[w] + (s - v);
        if (i < n) { row_ptr[i] = excl; counts_cursor[i] = excl; }
        carry += warp_total;
        __syncthreads();
    }
    if (t == 0) row_ptr[n] = carry;
}

__global__ void scatter_kernel(const int* __restrict__ dst, int* __restrict__ cursor,
                               int* __restrict__ perm, int E) {
    int i = blockIdx.x * blockDim.x + threadIdx.x;
    if (i < E) {
        int pos = atomicAdd(&cursor[dst[i]], 1);
        perm[pos] = i;
    }
}

// ---------------- GEMM 1: h1 = x @ W1   (M x 128) @ (128 x 128) ----------------
// 128x128 block tile, BK=32, 256 threads, 8x8 microtile per thread.

__global__ __launch_bounds__(256) void gemm_x_w1(const float* __restrict__ X,
                                                 const float* __restrict__ W,
                                                 float* __restrict__ H, int M) {
    __shared__ float xs[32][128 + 4];   // transposed: xs[k][r]
    __shared__ float wsh[32][128 + 4];  // wsh[k][c]
    const int tid = threadIdx.x;
    const int tx = tid & 15, ty = tid >> 4;
    const int row0 = blockIdx.x * 128;
    float acc[8][8] = {};
    for (int kk = 0; kk < IN_CH; kk += 32) {
        #pragma unroll
        for (int l = 0; l < 4; ++l) {
            int f = tid + l * 256;          // float4 id 0..1023 of X tile
            int r = f >> 3;                 // 0..127
            int c = (f & 7) << 2;           // 0..28
            int row = row0 + r;
            float4 v = make_float4(0.f, 0.f, 0.f, 0.f);
            if (row < M) v = *reinterpret_cast<const float4*>(&X[(size_t)row * IN_CH + kk + c]);
            xs[c + 0][r] = v.x; xs[c + 1][r] = v.y; xs[c + 2][r] = v.z; xs[c + 3][r] = v.w;
        }
        #pragma unroll
        for (int l = 0; l < 4; ++l) {
            int f = tid + l * 256;          // float4 id 0..1023 of W chunk (32x128)
            int r = f >> 5;                 // 0..31
            int c = (f & 31) << 2;          // 0..124
            float4 v = *reinterpret_cast<const float4*>(&W[(size_t)(kk + r) * HID_CH + c]);
            *reinterpret_cast<float4*>(&wsh[r][c]) = v;
        }
        __syncthreads();
        #pragma unroll
        for (int k = 0; k < 32; ++k) {
            float a[8], b[8];
            *reinterpret_cast<float4*>(&a[0]) = *reinterpret_cast<float4*>(&xs[k][ty * 8]);
            *reinterpret_cast<float4*>(&a[4]) = *reinterpret_cast<float4*>(&xs[k][ty * 8 + 4]);
            *reinterpret_cast<float4*>(&b[0]) = *reinterpret_cast<float4*>(&wsh[k][tx * 8]);
            *reinterpret_cast<float4*>(&b[4]) = *reinterpret_cast<float4*>(&wsh[k][tx * 8 + 4]);
            #pragma unroll
            for (int i = 0; i < 8; ++i)
                #pragma unroll
                for (int j = 0; j < 8; ++j)
                    acc[i][j] += a[i] * b[j];
        }
        __syncthreads();
    }
    #pragma unroll
    for (int i = 0; i < 8; ++i) {
        int row = row0 + ty * 8 + i;
        if (row < M) {
            #pragma unroll
            for (int j4 = 0; j4 < 2; ++j4) {
                float4 v = make_float4(acc[i][j4 * 4 + 0], acc[i][j4 * 4 + 1],
                                       acc[i][j4 * 4 + 2], acc[i][j4 * 4 + 3]);
                *reinterpret_cast<float4*>(&H[(size_t)row * HID_CH + tx * 8 + j4 * 4]) = v;
            }
        }
    }
}

// ---------------- GEMM 2: h2 = relu(g1) @ W2   (M x 128) @ (128 x 64) ----------------
// 128x64 block tile, BK=32, 256 threads, 8x4 microtile. ReLU fused into A load.

__global__ __launch_bounds__(256) void gemm_relu_w2(const float* __restrict__ G,
                                                    const float* __restrict__ W,
                                                    float* __restrict__ H, int M) {
    __shared__ float xs[32][128 + 4];   // transposed: xs[k][r]
    __shared__ float wsh[32][64 + 4];   // wsh[k][c]
    const int tid = threadIdx.x;
    const int tx = tid & 15, ty = tid >> 4;
    const int row0 = blockIdx.x * 128;
    float acc[8][4] = {};
    for (int kk = 0; kk < HID_CH; kk += 32) {
        #pragma unroll
        for (int l = 0; l < 4; ++l) {
            int f = tid + l * 256;
            int r = f >> 3;
            int c = (f & 7) << 2;
            int row = row0 + r;
            float4 v = make_float4(0.f, 0.f, 0.f, 0.f);
            if (row < M) v = *reinterpret_cast<const float4*>(&G[(size_t)row * HID_CH + kk + c]);
            xs[c + 0][r] = fmaxf(v.x, 0.f); xs[c + 1][r] = fmaxf(v.y, 0.f);
            xs[c + 2][r] = fmaxf(v.z, 0.f); xs[c + 3][r] = fmaxf(v.w, 0.f);
        }
        #pragma unroll
        for (int l = 0; l < 2; ++l) {
            int f = tid + l * 256;          // float4 id 0..511 of W chunk (32x64)
            int r = f >> 4;                 // 0..31
            int c = (f & 15) << 2;          // 0..60
            float4 v = *reinterpret_cast<const float4*>(&W[(size_t)(kk + r) * OUT_CH + c]);
            *reinterpret_cast<float4*>(&wsh[r][c]) = v;
        }
        __syncthreads();
        #pragma unroll
        for (int k = 0; k < 32; ++k) {
            float a[8], b[4];
            *reinterpret_cast<float4*>(&a[0]) = *reinterpret_cast<float4*>(&xs[k][ty * 8]);
            *reinterpret_cast<float4*>(&a[4]) = *reinterpret_cast<float4*>(&xs[k][ty * 8 + 4]);
            *reinterpret_cast<float4*>(&b[0]) = *reinterpret_cast<float4*>(&wsh[k][tx * 4]);
            #pragma unroll
            for (int i = 0; i < 8; ++i)
                #pragma unroll
                for (int j = 0; j < 4; ++j)
                    acc[i][j] += a[i] * b[j];
        }
        __syncthreads();
    }
    #pragma unroll
    for (int i = 0; i < 8; ++i) {
        int row = row0 + ty * 8 + i;
        if (row < M) {
            float4 v = make_float4(acc[i][0], acc[i][1], acc[i][2], acc[i][3]);
            *reinterpret_cast<float4*>(&H[(size_t)row * OUT_CH + tx * 4]) = v;
        }
    }
}

// ---------------- SpMM (CSR by dst): out[i] = sum_e val[e] * h[src[e]] ----------------
// D/4 threads per node, float4 gathers (coalesced 512B / 256B per edge).

template <int D>
__global__ __launch_bounds__(256) void spmm_csr(const int* __restrict__ row_ptr,
                                                const int* __restrict__ perm,
                                                const int* __restrict__ src,
                                                const float* __restrict__ vals,
                                                const float* __restrict__ h,
                                                float* __restrict__ out, int n) {
    constexpr int TPN = D / 4;       // threads per node
    constexpr int NPB = 256 / TPN;   // nodes per block
    int node = blockIdx.x * NPB + threadIdx.x / TPN;
    if (node >= n) return;
    int c4 = (threadIdx.x % TPN) * 4;
    int s = row_ptr[node], e = row_ptr[node + 1];
    float4 acc = make_float4(0.f, 0.f, 0.f, 0.f);
    for (int i = s; i < e; ++i) {
        int ed = perm[i];
        float v = vals[ed];
        int sr = src[ed];
        const float4 m = *reinterpret_cast<const float4*>(&h[(size_t)sr * D + c4]);
        acc.x += v * m.x; acc.y += v * m.y; acc.z += v * m.z; acc.w += v * m.w;
    }
    *reinterpret_cast<float4*>(&out[(size_t)node * D + c4]) = acc;
}

// ---------------- launch ----------------

extern "C" void kernel_launch(void* const* d_in, const int* in_sizes, int n_in,
                              void* d_out, int out_size, void* d_ws, size_t ws_size,
                              hipStream_t stream) {
    const float* x  = (const float*)d_in[0];
    const float* W1 = (const float*)d_in[1];
    const float* W2 = (const float*)d_in[2];
    const float* ev = (const float*)d_in[3];
    const int*   ei = (const int*)d_in[4];

    const int N = in_sizes[0] / IN_CH;   // 100000
    const int E = in_sizes[3];           // 1600000
    const int* src = ei;
    const int* dst = ei + E;

    // workspace layout (~110 MB): h1 | g1 | row_ptr | cursor | perm ; h2 reuses h1
    float* h1      = (float*)d_ws;                       // N*128 f32
    float* g1      = h1 + (size_t)N * HID_CH;            // N*128 f32
    int*   row_ptr = (int*)(g1 + (size_t)N * HID_CH);    // N+1 ints
    int*   cursor  = row_ptr + (N + 1);                  // N ints
    int*   perm    = cursor + N;                         // E ints
    float* h2      = h1;                                 // N*64 f32, reuse

    // CSR build (reused by both SpMM layers)
    hipMemsetAsync(cursor, 0, (size_t)N * sizeof(int), stream);
    hist_kernel<<<(E + 255) / 256, 256, 0, stream>>>(dst, cursor, E);
    scan_kernel<<<1, 1024, 0, stream>>>(cursor, row_ptr, N);
    scatter_kernel<<<(E + 255) / 256, 256, 0, stream>>>(dst, cursor, perm, E);

    // layer 1
    gemm_x_w1<<<(N + 127) / 128, 256, 0, stream>>>(x, W1, h1, N);
    spmm_csr<HID_CH><<<(N + 7) / 8, 256, 0, stream>>>(row_ptr, perm, src, ev, h1, g1, N);

    // layer 2 (relu fused into GEMM2's A load)
    gemm_relu_w2<<<(N + 127) / 128, 256, 0, stream>>>(g1, W2, h2, N);
    spmm_csr<OUT_CH><<<(N + 15) / 16, 256, 0, stream>>>(row_ptr, perm, src, ev, h2, (float*)d_out, N);
}

// Round 4
// 319.788 us; speedup vs baseline: 2.2022x; 2.2022x over previous
//
#include <hip/hip_runtime.h>

// VanillaGNN: out = A @ relu(A @ (x@W1)) @ W2, A[dst,src]=vals, all inputs f32.
// N=100000, E=1600000, IN=128, HID=128, OUT=64.
// Plan: CSR build (hist + multiblock scan + scatter w/ materialized src/vals),
// bf16 MFMA GEMMs, bf16-payload SpMM with 4x-unrolled gather ILP.

#define IN_CH  128
#define HID_CH 128
#define OUT_CH 64

typedef __attribute__((ext_vector_type(8))) short  bfrag8;   // 8 bf16 (MFMA A/B)
typedef __attribute__((ext_vector_type(4))) float  f32x4;    // MFMA C/D
typedef __attribute__((ext_vector_type(4))) unsigned short us4;
typedef __attribute__((ext_vector_type(8))) unsigned short us8;

__device__ __forceinline__ unsigned short f2bf(float f) {
    unsigned u = __float_as_uint(f);
    u += 0x7FFFu + ((u >> 16) & 1u);   // round-to-nearest-even
    return (unsigned short)(u >> 16);
}
__device__ __forceinline__ float bf2f(unsigned short u) {
    return __uint_as_float(((unsigned)u) << 16);
}

// ---------------- CSR build ----------------

__global__ void hist_kernel(const int* __restrict__ dst, int* __restrict__ counts, int E) {
    int i = blockIdx.x * blockDim.x + threadIdx.x;
    if (i < E) atomicAdd(&counts[dst[i]], 1);
}

// Per-chunk exclusive scan: excl[i] = local exclusive prefix, btot[b] = chunk sum.
__global__ __launch_bounds__(1024) void scanA(const int* __restrict__ counts,
                                              int* __restrict__ excl,
                                              int* __restrict__ btot, int n) {
    __shared__ int wex[16];
    int t = threadIdx.x, lane = t & 63, w = t >> 6;
    int i = blockIdx.x * 1024 + t;
    int v = (i < n) ? counts[i] : 0;
    int s = v;
    #pragma unroll
    for (int d = 1; d < 64; d <<= 1) {
        int u = __shfl_up(s, d, 64);
        if (lane >= d) s += u;
    }
    if (lane == 63) wex[w] = s;
    __syncthreads();
    if (t == 0) {
        int run = 0;
        #pragma unroll
        for (int j = 0; j < 16; ++j) { int x = wex[j]; wex[j] = run; run += x; }
        btot[blockIdx.x] = run;
    }
    __syncthreads();
    if (i < n) excl[i] = wex[w] + (s - v);
}

// Exclusive scan of chunk totals (nblk <= 128), one block of 128 threads.
__global__ __launch_bounds__(128) void scanB(int* __restrict__ btot, int nblk) {
    __shared__ int t0;
    int t = threadIdx.x, lane = t & 63, w = t >> 6;
    int v = (t < nblk) ? btot[t] : 0;
    int s = v;
    #pragma unroll
    for (int d = 1; d < 64; d <<= 1) {
        int u = __shfl_up(s, d, 64);
        if (lane >= d) s += u;
    }
    if (w == 0 && lane == 63) t0 = s;
    __syncthreads();
    int excl = (s - v) + (w ? t0 : 0);
    if (t < nblk) btot[t] = excl;
}

// Add chunk offsets: row_ptr[i] final, cursor[i] = same (scatter cursors).
__global__ __launch_bounds__(1024) void scanC(int* __restrict__ row_ptr,
                                              int* __restrict__ cursor,
                                              const int* __restrict__ btot, int n, int E) {
    int i = blockIdx.x * 1024 + threadIdx.x;
    if (i < n) {
        int e = row_ptr[i] + btot[blockIdx.x];
        row_ptr[i] = e;
        cursor[i] = e;
    }
    if (i == 0) row_ptr[n] = E;
}

// Scatter edges into dst-sorted order, materializing src & vals (no perm indirection).
__global__ void scatter_kernel(const int* __restrict__ src, const int* __restrict__ dst,
                               const float* __restrict__ ev, int* __restrict__ cursor,
                               int* __restrict__ srcs, float* __restrict__ vsorted, int E) {
    int i = blockIdx.x * blockDim.x + threadIdx.x;
    if (i < E) {
        int pos = atomicAdd(&cursor[dst[i]], 1);
        srcs[pos] = src[i];
        vsorted[pos] = ev[i];
    }
}

// ---------------- weight cast+transpose (tiny) ----------------

__global__ void castT_w1(const float* __restrict__ W, unsigned short* __restrict__ WT) {
    int idx = blockIdx.x * 256 + threadIdx.x;          // 16384 elems
    int n = idx >> 7, k = idx & 127;                   // WT[n][k] = W[k][n]
    WT[n * 128 + k] = f2bf(W[k * 128 + n]);
}
__global__ void castT_w2(const float* __restrict__ W, unsigned short* __restrict__ WT) {
    int idx = blockIdx.x * 256 + threadIdx.x;          // 8192 elems
    int n = idx >> 7, k = idx & 127;                   // WT[n][k] = W[k][64: n]
    WT[n * 128 + k] = f2bf(W[(size_t)k * OUT_CH + n]);
}

// ---------------- GEMM1: h1 = bf16(x @ W1), MFMA 16x16x32 ----------------
// Block 128x128, 4 waves, wave tile 32x128 (2x8 mtiles). K=128 (no K loop).

__global__ __launch_bounds__(256) void gemm1_mfma(const float* __restrict__ X,
                                                  const unsigned short* __restrict__ W1T,
                                                  unsigned short* __restrict__ H1, int M) {
    __shared__ __align__(16) unsigned short As[128 * 136];  // [row][k], stride 136 (pad)
    __shared__ __align__(16) unsigned short Bs[128 * 136];  // [n][k]
    const int tid = threadIdx.x;
    const int lane = tid & 63;
    const int w = tid >> 6;
    const int row0 = blockIdx.x * 128;

    // stage A: 128x128 f32 -> bf16 (4096 float4 reads)
    #pragma unroll
    for (int l = 0; l < 16; ++l) {
        int f = tid + l * 256;
        int r = f >> 5, c4 = f & 31;
        int row = row0 + r;
        float4 v = make_float4(0.f, 0.f, 0.f, 0.f);
        if (row < M) v = *reinterpret_cast<const float4*>(&X[(size_t)row * IN_CH + c4 * 4]);
        us4 o; o[0] = f2bf(v.x); o[1] = f2bf(v.y); o[2] = f2bf(v.z); o[3] = f2bf(v.w);
        *reinterpret_cast<us4*>(&As[r * 136 + c4 * 4]) = o;
    }
    // stage B: W1T 128x128 bf16 (2048 ushort8 reads)
    #pragma unroll
    for (int l = 0; l < 8; ++l) {
        int f = tid + l * 256;
        int n = f >> 4, k8 = f & 15;
        us8 v = *reinterpret_cast<const us8*>(&W1T[n * 128 + k8 * 8]);
        *reinterpret_cast<us8*>(&Bs[n * 136 + k8 * 8]) = v;
    }
    __syncthreads();

    f32x4 acc[2][8] = {};
    const int lr = lane & 15;
    const int kb = (lane >> 4) * 8;
    #pragma unroll
    for (int kk = 0; kk < 4; ++kk) {
        bfrag8 a0 = *reinterpret_cast<const bfrag8*>(&As[(w * 32 + lr) * 136 + kk * 32 + kb]);
        bfrag8 a1 = *reinterpret_cast<const bfrag8*>(&As[(w * 32 + 16 + lr) * 136 + kk * 32 + kb]);
        #pragma unroll
        for (int ni = 0; ni < 8; ++ni) {
            bfrag8 b = *reinterpret_cast<const bfrag8*>(&Bs[(ni * 16 + lr) * 136 + kk * 32 + kb]);
            acc[0][ni] = __builtin_amdgcn_mfma_f32_16x16x32_bf16(a0, b, acc[0][ni], 0, 0, 0);
            acc[1][ni] = __builtin_amdgcn_mfma_f32_16x16x32_bf16(a1, b, acc[1][ni], 0, 0, 0);
        }
    }
    // epilogue: C row = (lane>>4)*4 + j, col = lane&15 within each 16x16 tile
    const int rb = row0 + w * 32 + (lane >> 4) * 4;
    #pragma unroll
    for (int mi = 0; mi < 2; ++mi)
        #pragma unroll
        for (int j = 0; j < 4; ++j) {
            int row = rb + mi * 16 + j;
            if (row < M) {
                #pragma unroll
                for (int ni = 0; ni < 8; ++ni)
                    H1[(size_t)row * HID_CH + ni * 16 + lr] = f2bf(acc[mi][ni][j]);
            }
        }
}

// ---------------- GEMM2: h2 = bf16(g1r @ W2), A already bf16 (relu pre-applied) ----------------
// Block 128x64, 4 waves, wave tile 32x64 (2x4 mtiles). K=128.

__global__ __launch_bounds__(256) void gemm2_mfma(const unsigned short* __restrict__ G,
                                                  const unsigned short* __restrict__ W2T,
                                                  unsigned short* __restrict__ H2, int M) {
    __shared__ __align__(16) unsigned short As[128 * 136];
    __shared__ __align__(16) unsigned short Bs[64 * 136];
    const int tid = threadIdx.x;
    const int lane = tid & 63;
    const int w = tid >> 6;
    const int row0 = blockIdx.x * 128;

    #pragma unroll
    for (int l = 0; l < 8; ++l) {
        int f = tid + l * 256;                 // 2048 ushort8
        int r = f >> 4, k8 = f & 15;
        int row = row0 + r;
        us8 v{};
        if (row < M) v = *reinterpret_cast<const us8*>(&G[(size_t)row * HID_CH + k8 * 8]);
        *reinterpret_cast<us8*>(&As[r * 136 + k8 * 8]) = v;
    }
    #pragma unroll
    for (int l = 0; l < 4; ++l) {
        int f = tid + l * 256;                 // 1024 ushort8
        int n = f >> 4, k8 = f & 15;
        us8 v = *reinterpret_cast<const us8*>(&W2T[n * 128 + k8 * 8]);
        *reinterpret_cast<us8*>(&Bs[n * 136 + k8 * 8]) = v;
    }
    __syncthreads();

    f32x4 acc[2][4] = {};
    const int lr = lane & 15;
    const int kb = (lane >> 4) * 8;
    #pragma unroll
    for (int kk = 0; kk < 4; ++kk) {
        bfrag8 a0 = *reinterpret_cast<const bfrag8*>(&As[(w * 32 + lr) * 136 + kk * 32 + kb]);
        bfrag8 a1 = *reinterpret_cast<const bfrag8*>(&As[(w * 32 + 16 + lr) * 136 + kk * 32 + kb]);
        #pragma unroll
        for (int ni = 0; ni < 4; ++ni) {
            bfrag8 b = *reinterpret_cast<const bfrag8*>(&Bs[(ni * 16 + lr) * 136 + kk * 32 + kb]);
            acc[0][ni] = __builtin_amdgcn_mfma_f32_16x16x32_bf16(a0, b, acc[0][ni], 0, 0, 0);
            acc[1][ni] = __builtin_amdgcn_mfma_f32_16x16x32_bf16(a1, b, acc[1][ni], 0, 0, 0);
        }
    }
    const int rb = row0 + w * 32 + (lane >> 4) * 4;
    #pragma unroll
    for (int mi = 0; mi < 2; ++mi)
        #pragma unroll
        for (int j = 0; j < 4; ++j) {
            int row = rb + mi * 16 + j;
            if (row < M) {
                #pragma unroll
                for (int ni = 0; ni < 4; ++ni)
                    H2[(size_t)row * OUT_CH + ni * 16 + lr] = f2bf(acc[mi][ni][j]);
            }
        }
}

// ---------------- SpMM: out[i] = sum_e vals[e] * h[srcs[e]], bf16 payload ----------------
// D/8 lanes per node, us8 (16B) gathers, 4x unrolled for gather ILP.
// MODE 0: out = f32. MODE 1: out = bf16(relu(acc)).

template <int D, int MODE>
__global__ __launch_bounds__(256) void spmm_bf16(const int* __restrict__ row_ptr,
                                                 const int* __restrict__ srcs,
                                                 const float* __restrict__ vsorted,
                                                 const unsigned short* __restrict__ h,
                                                 void* __restrict__ outp, int n) {
    constexpr int TPN = D / 8;
    constexpr int NPB = 256 / TPN;
    int node = blockIdx.x * NPB + threadIdx.x / TPN;
    if (node >= n) return;
    int c8 = (threadIdx.x % TPN) * 8;
    int s = row_ptr[node], e = row_ptr[node + 1];
    float acc[8] = {};
    int i = s;
    for (; i + 4 <= e; i += 4) {
        int sr0 = srcs[i + 0], sr1 = srcs[i + 1], sr2 = srcs[i + 2], sr3 = srcs[i + 3];
        float v0 = vsorted[i + 0], v1 = vsorted[i + 1];
        float v2 = vsorted[i + 2], v3 = vsorted[i + 3];
        us8 m0 = *reinterpret_cast<const us8*>(&h[(size_t)sr0 * D + c8]);
        us8 m1 = *reinterpret_cast<const us8*>(&h[(size_t)sr1 * D + c8]);
        us8 m2 = *reinterpret_cast<const us8*>(&h[(size_t)sr2 * D + c8]);
        us8 m3 = *reinterpret_cast<const us8*>(&h[(size_t)sr3 * D + c8]);
        #pragma unroll
        for (int j = 0; j < 8; ++j) {
            acc[j] += v0 * bf2f(m0[j]);
            acc[j] += v1 * bf2f(m1[j]);
            acc[j] += v2 * bf2f(m2[j]);
            acc[j] += v3 * bf2f(m3[j]);
        }
    }
    for (; i < e; ++i) {
        int sr = srcs[i];
        float v = vsorted[i];
        us8 m = *reinterpret_cast<const us8*>(&h[(size_t)sr * D + c8]);
        #pragma unroll
        for (int j = 0; j < 8; ++j) acc[j] += v * bf2f(m[j]);
    }
    if (MODE == 1) {
        us8 o;
        #pragma unroll
        for (int j = 0; j < 8; ++j) o[j] = f2bf(fmaxf(acc[j], 0.f));
        *reinterpret_cast<us8*>(&((unsigned short*)outp)[(size_t)node * D + c8]) = o;
    } else {
        float* op = (float*)outp;
        float4 w0 = make_float4(acc[0], acc[1], acc[2], acc[3]);
        float4 w1 = make_float4(acc[4], acc[5], acc[6], acc[7]);
        *reinterpret_cast<float4*>(&op[(size_t)node * D + c8]) = w0;
        *reinterpret_cast<float4*>(&op[(size_t)node * D + c8 + 4]) = w1;
    }
}

// ---------------- launch ----------------

extern "C" void kernel_launch(void* const* d_in, const int* in_sizes, int n_in,
                              void* d_out, int out_size, void* d_ws, size_t ws_size,
                              hipStream_t stream) {
    const float* x  = (const float*)d_in[0];
    const float* W1 = (const float*)d_in[1];
    const float* W2 = (const float*)d_in[2];
    const float* ev = (const float*)d_in[3];
    const int*   ei = (const int*)d_in[4];

    const int N = in_sizes[0] / IN_CH;   // 100000
    const int E = in_sizes[3];           // 1600000
    const int* src = ei;
    const int* dst = ei + E;

    // workspace layout (~78 MB), bf16 segments first (keeps 16B alignment)
    unsigned short* h1   = (unsigned short*)d_ws;        // N*128 bf16
    unsigned short* g1r  = h1 + (size_t)N * HID_CH;      // N*128 bf16 (relu applied)
    unsigned short* h2   = g1r + (size_t)N * HID_CH;     // N*64 bf16
    unsigned short* w1t  = h2 + (size_t)N * OUT_CH;      // 128*128 bf16 [n][k]
    unsigned short* w2t  = w1t + 128 * 128;              // 64*128 bf16 [n][k]
    int*   srcs    = (int*)(w2t + 64 * 128);             // E
    float* vsorted = (float*)(srcs + E);                 // E
    int*   row_ptr = (int*)(vsorted + E);                // N+1
    int*   cursor  = row_ptr + (N + 1);                  // N (also the histogram)
    int*   btot    = cursor + N;                         // scan chunk totals (<=128)

    const int nchunk = (N + 1023) / 1024;                // 98

    // CSR build
    hipMemsetAsync(cursor, 0, (size_t)N * sizeof(int), stream);
    hist_kernel<<<(E + 255) / 256, 256, 0, stream>>>(dst, cursor, E);
    scanA<<<nchunk, 1024, 0, stream>>>(cursor, row_ptr, btot, N);
    scanB<<<1, 128, 0, stream>>>(btot, nchunk);
    scanC<<<nchunk, 1024, 0, stream>>>(row_ptr, cursor, btot, N, E);
    scatter_kernel<<<(E + 255) / 256, 256, 0, stream>>>(src, dst, ev, cursor, srcs, vsorted, E);

    // weights: cast + transpose to [n][k] bf16
    castT_w1<<<64, 256, 0, stream>>>(W1, w1t);
    castT_w2<<<32, 256, 0, stream>>>(W2, w2t);

    // layer 1
    gemm1_mfma<<<(N + 127) / 128, 256, 0, stream>>>(x, w1t, h1, N);
    spmm_bf16<HID_CH, 1><<<(N + 15) / 16, 256, 0, stream>>>(row_ptr, srcs, vsorted, h1, g1r, N);

    // layer 2
    gemm2_mfma<<<(N + 127) / 128, 256, 0, stream>>>(g1r, w2t, h2, N);
    spmm_bf16<OUT_CH, 0><<<(N + 31) / 32, 256, 0, stream>>>(row_ptr, srcs, vsorted, h2, (float*)d_out, N);
}